// Round 13
// baseline (530.798 us; speedup 1.0000x reference)
//
#include <hip/hip_runtime.h>
#include <math.h>

// ---------------------------------------------------------------------------
// FlashSVD LLaMA block, round 13: r12 kernels verbatim (gemm8w = 8-wave
// 128x128/BK=64, 48KB LDS, 3 blk/CU — proven 507us). Change = launch geometry
// only: every K-heavy GEMM now launches >=512 blocks (gemm8w capacity is 768
// resident): dV split 7->14, xrq 4->8, oV 4->8, gV/uV 4->8, kV/vV 4->8, and
// oUs/dUs split 2 via new reduce_addf (sum planes + residual). PARTSZ 128MB.
// ---------------------------------------------------------------------------

typedef __bf16 bf16;
typedef __bf16 bf16x8 __attribute__((ext_vector_type(8)));
typedef __bf16 bf16x4 __attribute__((ext_vector_type(4)));
typedef float  f32x4  __attribute__((ext_vector_type(4)));

#define EPI_BF16   0
#define EPI_BF16T  1   // transposed bf16 store (V in [d][t] layout)
#define EPI_F32ADD 2   // fp32 store with residual add
#define EPI_SILU1  3   // store silu(acc) bf16
#define EPI_MUL    4   // RMW: C *= acc (bf16)
#define EPI_PART   5   // fp32 partial plane store (split-K)

__device__ __forceinline__ void gld16(const void* g, void* l) {
    __builtin_amdgcn_global_load_lds(
        (const __attribute__((address_space(1))) unsigned int*)g,
        (__attribute__((address_space(3))) unsigned int*)l, 16, 0, 0);
}

// ---------------------------------------------------------------------------
// gemm8w: A bf16 [M,K], B fp32 [N,K], 128x128 tile, BK=64, 8 waves (2M x 4N,
// wave tile 64x32), single-buffered 48KB LDS -> 3 blk/CU = 24 waves/CU,
// 2 barriers/K-step, both operands via global_load_lds, source pre-swizzled
// (A: chunk8 ^= row&7; B: chunk16 ^= row&15), matching XOR on reads.
// Grid: dim3(nwg,1,z); XCD-bijective remap; bm=id%gx, bn=id/gx.
// grid.z = batch*nsplit; zb selects B2 when given (two GEMMs sharing A).
// ---------------------------------------------------------------------------
template<int EPI>
__global__ __launch_bounds__(512)
void gemm8w(const bf16* __restrict__ A, int lda, long sA,
            const float* __restrict__ B, int ldb, long sB, const float* __restrict__ B2,
            void* __restrict__ Cv, int ldc, long sC,
            const float* __restrict__ R, int Kc, int nsplit, int gx)
{
    __shared__ __align__(16) bf16  As[128 * 64];   // 16 KB
    __shared__ __align__(16) float Bs[128 * 64];   // 32 KB

    const int tid = threadIdx.x, lane = tid & 63, w = tid >> 6;  // 8 waves
    const int wr = w >> 2, wcn = w & 3;            // 2M x 4N, wave tile 64x32

    int id = blockIdx.x;
    {   // bijective XCD remap (m204)
        const int nwg = gridDim.x;
        int q = nwg >> 3, rr = nwg & 7;
        int xcd = id & 7, off = id >> 3;
        id = (xcd < rr ? xcd * (q + 1) : rr * (q + 1) + (xcd - rr) * q) + off;
    }
    const int bm = id % gx, bn = id / gx, bz = blockIdx.z;
    const int ks = bz % nsplit, zb = bz / nsplit;

    const float* Bp = (B2 != nullptr && zb != 0) ? B2 : B;
    const bf16*  Ab = A  + (long)zb * sA + (long)(bm * 128) * lda + (long)ks * Kc;
    const float* Bb = Bp + (long)zb * sB + (long)(bn * 128) * ldb + (long)ks * Kc;

    const int g = lane >> 4, r = lane & 15;
    f32x4 acc[4][2] = {};
    const int nt = Kc >> 6;

    for (int t = 0; t < nt; t++) {
        if (t) __syncthreads();
        const bf16*  At = Ab + t * 64;
        const float* Bt = Bb + t * 64;
        // A: 1024 16B-chunks (8/row); slot ci holds global chunk (ci&7)^(row&7)
        #pragma unroll
        for (int i = 0; i < 2; i++) {
            int cb = w * 128 + i * 64, ci = cb + lane;
            int row = ci >> 3, col = ((ci & 7) ^ (row & 7)) * 8;
            gld16(At + (long)row * lda + col, &As[cb * 8]);
        }
        // B: 2048 16B-chunks (16/row); slot ci holds global chunk (ci&15)^(row&15)
        #pragma unroll
        for (int i = 0; i < 4; i++) {
            int cb = w * 256 + i * 64, ci = cb + lane;
            int row = ci >> 4, col = ((ci & 15) ^ (row & 15)) * 4;
            gld16(Bt + (long)row * ldb + col, &Bs[cb * 4]);
        }
        __syncthreads();
        #pragma unroll
        for (int kk = 0; kk < 2; kk++) {
            bf16x8 af[4], bfr[2];
            #pragma unroll
            for (int m = 0; m < 4; m++) {
                int row = wr * 64 + m * 16 + r;
                af[m] = *(const bf16x8*)&As[row * 64 + (((kk * 4 + g) ^ (row & 7)) * 8)];
            }
            #pragma unroll
            for (int n = 0; n < 2; n++) {
                int row = wcn * 32 + n * 16 + r;
                int c0 = kk * 8 + g * 2;
                f32x4 lo = *(const f32x4*)&Bs[row * 64 + (((c0    ) ^ (row & 15)) * 4)];
                f32x4 hi = *(const f32x4*)&Bs[row * 64 + (((c0 + 1) ^ (row & 15)) * 4)];
                bfr[n] = bf16x8{(bf16)lo[0], (bf16)lo[1], (bf16)lo[2], (bf16)lo[3],
                                (bf16)hi[0], (bf16)hi[1], (bf16)hi[2], (bf16)hi[3]};
            }
            #pragma unroll
            for (int m = 0; m < 4; m++)
                #pragma unroll
                for (int n = 0; n < 2; n++)
                    acc[m][n] = __builtin_amdgcn_mfma_f32_16x16x32_bf16(af[m], bfr[n], acc[m][n], 0, 0, 0);
        }
    }

    // epilogue: C layout col = lane&15, row = (lane>>4)*4 + j
    #pragma unroll
    for (int m = 0; m < 4; m++) {
        #pragma unroll
        for (int n = 0; n < 2; n++) {
            const int row0 = bm * 128 + wr * 64 + m * 16 + g * 4;
            const int col  = bn * 128 + wcn * 32 + n * 16 + r;
            #pragma unroll
            for (int j = 0; j < 4; j++) {
                float v = acc[m][n][j];
                long row = row0 + j;
                if constexpr (EPI == EPI_BF16) {
                    ((bf16*)Cv)[(long)zb * sC + row * (long)ldc + col] = (bf16)v;
                } else if constexpr (EPI == EPI_BF16T) {
                    ((bf16*)Cv)[(long)zb * sC + (long)col * ldc + row] = (bf16)v;
                } else if constexpr (EPI == EPI_F32ADD) {
                    long idx = row * (long)ldc + col;
                    ((float*)Cv)[idx] = v + R[idx];
                } else if constexpr (EPI == EPI_PART) {
                    ((float*)Cv)[(long)bz * sC + row * (long)ldc + col] = v;
                } else if constexpr (EPI == EPI_SILU1) {
                    ((bf16*)Cv)[row * (long)ldc + col] = (bf16)(v / (1.f + __expf(-v)));
                } else { // EPI_MUL
                    bf16* p = &((bf16*)Cv)[row * (long)ldc + col];
                    *p = (bf16)((float)*p * v);
                }
            }
        }
    }
}

// ---------------------------------------------------------------------------
// gemm2 (fallback for small workspace): fp32 B converted in staging, dbuf.
// ---------------------------------------------------------------------------
template<int EPI>
__global__ __launch_bounds__(256)
void gemm2(const bf16* __restrict__ A, int lda, long sA,
           const float* __restrict__ B, int ldb, long sB, const float* __restrict__ B2,
           void* __restrict__ Cv, int ldc, long sC,
           const float* __restrict__ R, int Kc, int nsplit)
{
    __shared__ __align__(16) bf16 As[2][128 * 64];
    __shared__ __align__(16) bf16 Bs[2][128 * 64];

    const int tid = threadIdx.x, lane = tid & 63, w = tid >> 6;
    const int wr = w >> 1, wc = w & 1;
    const int bm = blockIdx.x, bn = blockIdx.y, bz = blockIdx.z;
    const int ks = bz % nsplit, zb = bz / nsplit;

    const float* Bp = (B2 != nullptr && zb != 0) ? B2 : B;
    const bf16*  Ab = A  + (long)zb * sA + (long)(bm * 128) * lda + (long)ks * Kc;
    const float* Bb = Bp + (long)zb * sB + (long)(bn * 128) * ldb + (long)ks * Kc;

    const int g = lane >> 4, r = lane & 15;
    f32x4 acc[4][4] = {};
    const int nt = Kc >> 6;
    int cur = 0;

    {
        #pragma unroll
        for (int i = 0; i < 4; i++) {
            int cb = i * 256 + w * 64, ci = cb + lane;
            int arow = ci >> 3, acol = ((ci & 7) ^ (arow & 7)) * 8;
            gld16(Ab + (long)arow * lda + acol, &As[0][cb * 8]);
        }
        float4 fb[8];
        #pragma unroll
        for (int i = 0; i < 8; i++) {
            int p = i * 256 + tid;
            fb[i] = *(const float4*)(Bb + (long)(p >> 4) * ldb + (p & 15) * 4);
        }
        #pragma unroll
        for (int i = 0; i < 8; i++) {
            int p = i * 256 + tid, brow = p >> 4, c4 = p & 15;
            bf16x4 h = {(bf16)fb[i].x, (bf16)fb[i].y, (bf16)fb[i].z, (bf16)fb[i].w};
            *(bf16x4*)&Bs[0][brow * 64 + (((c4 >> 1) ^ (brow & 7)) * 8) + (c4 & 1) * 4] = h;
        }
    }
    __syncthreads();

    for (int t = 0; t < nt; t++) {
        float4 fb[8];
        if (t + 1 < nt) {
            const bf16* An = Ab + (t + 1) * 64;
            #pragma unroll
            for (int i = 0; i < 4; i++) {
                int cb = i * 256 + w * 64, ci = cb + lane;
                int arow = ci >> 3, acol = ((ci & 7) ^ (arow & 7)) * 8;
                gld16(An + (long)arow * lda + acol, &As[cur ^ 1][cb * 8]);
            }
            const float* Bn = Bb + (t + 1) * 64;
            #pragma unroll
            for (int i = 0; i < 8; i++) {
                int p = i * 256 + tid;
                fb[i] = *(const float4*)(Bn + (long)(p >> 4) * ldb + (p & 15) * 4);
            }
        }
        #pragma unroll
        for (int kk = 0; kk < 2; kk++) {
            bf16x8 af[4], bfr[4];
            #pragma unroll
            for (int m = 0; m < 4; m++) {
                int row = wr * 64 + m * 16 + r;
                af[m] = *(const bf16x8*)&As[cur][row * 64 + (((kk * 4 + g) ^ (row & 7)) * 8)];
            }
            #pragma unroll
            for (int n = 0; n < 4; n++) {
                int row = wc * 64 + n * 16 + r;
                bfr[n] = *(const bf16x8*)&Bs[cur][row * 64 + (((kk * 4 + g) ^ (row & 7)) * 8)];
            }
            #pragma unroll
            for (int m = 0; m < 4; m++)
                #pragma unroll
                for (int n = 0; n < 4; n++)
                    acc[m][n] = __builtin_amdgcn_mfma_f32_16x16x32_bf16(af[m], bfr[n], acc[m][n], 0, 0, 0);
        }
        if (t + 1 < nt) {
            #pragma unroll
            for (int i = 0; i < 8; i++) {
                int p = i * 256 + tid, brow = p >> 4, c4 = p & 15;
                bf16x4 h = {(bf16)fb[i].x, (bf16)fb[i].y, (bf16)fb[i].z, (bf16)fb[i].w};
                *(bf16x4*)&Bs[cur ^ 1][brow * 64 + (((c4 >> 1) ^ (brow & 7)) * 8) + (c4 & 1) * 4] = h;
            }
            __syncthreads();
            cur ^= 1;
        }
    }

    #pragma unroll
    for (int m = 0; m < 4; m++) {
        #pragma unroll
        for (int n = 0; n < 4; n++) {
            const int row0 = bm * 128 + wr * 64 + m * 16 + g * 4;
            const int col  = bn * 128 + wc * 64 + n * 16 + r;
            #pragma unroll
            for (int j = 0; j < 4; j++) {
                float v = acc[m][n][j];
                long row = row0 + j;
                if constexpr (EPI == EPI_BF16) {
                    ((bf16*)Cv)[(long)zb * sC + row * (long)ldc + col] = (bf16)v;
                } else if constexpr (EPI == EPI_BF16T) {
                    ((bf16*)Cv)[(long)zb * sC + (long)col * ldc + row] = (bf16)v;
                } else if constexpr (EPI == EPI_F32ADD) {
                    long idx = row * (long)ldc + col;
                    ((float*)Cv)[idx] = v + R[idx];
                } else if constexpr (EPI == EPI_PART) {
                    ((float*)Cv)[(long)bz * sC + row * (long)ldc + col] = v;
                } else if constexpr (EPI == EPI_SILU1) {
                    ((bf16*)Cv)[row * (long)ldc + col] = (bf16)(v / (1.f + __expf(-v)));
                } else {
                    bf16* p = &((bf16*)Cv)[row * (long)ldc + col];
                    *p = (bf16)((float)*p * v);
                }
            }
        }
    }
}

// ---------------------------------------------------------------------------
__global__ __launch_bounds__(256)
void reduce_k(const float* __restrict__ part, long pe, int np, bf16* __restrict__ out)
{
    long i = ((long)blockIdx.x * 256 + threadIdx.x) * 4;
    float4 s = *(const float4*)&part[i];
    for (int p = 1; p < np; p++) {
        float4 v = *(const float4*)&part[(long)p * pe + i];
        s.x += v.x; s.y += v.y; s.z += v.z; s.w += v.w;
    }
    bf16x4 o = {(bf16)s.x, (bf16)s.y, (bf16)s.z, (bf16)s.w};
    *(bf16x4*)&out[i] = o;
}

// sum np fp32 planes + residual -> fp32 out (for the oUs/dUs epilogues)
__global__ __launch_bounds__(256)
void reduce_addf(const float* __restrict__ part, long pe, int np,
                 const float* __restrict__ R, float* __restrict__ out)
{
    long i = ((long)blockIdx.x * 256 + threadIdx.x) * 4;
    float4 s = *(const float4*)&part[i];
    for (int p = 1; p < np; p++) {
        float4 v = *(const float4*)&part[(long)p * pe + i];
        s.x += v.x; s.y += v.y; s.z += v.z; s.w += v.w;
    }
    float4 rr = *(const float4*)&R[i];
    s.x += rr.x; s.y += rr.y; s.z += rr.z; s.w += rr.w;
    *(float4*)&out[i] = s;
}

__global__ __launch_bounds__(256)
void rmsnorm_k(const float* __restrict__ x, const float* __restrict__ w,
               bf16* __restrict__ out)
{
    const int D = 4096;
    const long row = blockIdx.x;
    const float* xr = x + row * D;
    float4 v[4];
    float ss = 0.f;
    #pragma unroll
    for (int k = 0; k < 4; k++) {
        v[k] = *(const float4*)&xr[threadIdx.x * 4 + k * 1024];
        ss += v[k].x * v[k].x + v[k].y * v[k].y + v[k].z * v[k].z + v[k].w * v[k].w;
    }
    #pragma unroll
    for (int o = 32; o > 0; o >>= 1) ss += __shfl_down(ss, o);
    __shared__ float red[4];
    if ((threadIdx.x & 63) == 0) red[threadIdx.x >> 6] = ss;
    __syncthreads();
    float rs = rsqrtf((red[0] + red[1] + red[2] + red[3]) / D + 1e-5f);
    #pragma unroll
    for (int k = 0; k < 4; k++) {
        int i = threadIdx.x * 4 + k * 1024;
        float4 wv = *(const float4*)&w[i];
        bf16x4 o4 = {(bf16)(v[k].x * rs * wv.x), (bf16)(v[k].y * rs * wv.y),
                     (bf16)(v[k].z * rs * wv.z), (bf16)(v[k].w * rs * wv.w)};
        *(bf16x4*)&out[row * D + i] = o4;
    }
}

__global__ __launch_bounds__(256)
void rope_table_k(float* cs, float* sn)
{
    int idx = blockIdx.x * blockDim.x + threadIdx.x;  // 1024*64
    int t = idx >> 6, i = idx & 63;
    float inv = powf(10000.0f, -(2.0f * i) / 128.0f);
    float a = (float)t * inv;
    cs[idx] = cosf(a);
    sn[idx] = sinf(a);
}

// rope, vectorized: each thread owns 8 d-pairs (16B loads/stores).
__global__ __launch_bounds__(256)
void rope_k(bf16* qk, const float* __restrict__ cs, const float* __restrict__ sn)
{
    long idx = (long)blockIdx.x * blockDim.x + threadIdx.x;  // nh*1024*8
    int d0 = (int)(idx & 7) * 8;          // 0,8,..,56
    long ht = idx >> 3;
    int t = (int)(ht & 1023);
    bf16* p = qk + ht * 128;
    bf16x8 x1 = *(const bf16x8*)(p + d0);
    bf16x8 x2 = *(const bf16x8*)(p + d0 + 64);
    int i0 = d0 >> 1;                      // 4 angle idxs, each used twice
    float4 c1 = *(const float4*)&cs[t * 64 + i0];
    float4 s1 = *(const float4*)&sn[t * 64 + i0];
    float4 c2 = *(const float4*)&cs[t * 64 + 32 + i0];
    float4 s2 = *(const float4*)&sn[t * 64 + 32 + i0];
    float c1a[4] = {c1.x, c1.y, c1.z, c1.w}, s1a[4] = {s1.x, s1.y, s1.z, s1.w};
    float c2a[4] = {c2.x, c2.y, c2.z, c2.w}, s2a[4] = {s2.x, s2.y, s2.z, s2.w};
    bf16x8 o1, o2;
    #pragma unroll
    for (int j = 0; j < 8; j++) {
        float a = (float)x1[j], b = (float)x2[j];
        int q = j >> 1;
        o1[j] = (bf16)(a * c1a[q] - b * s1a[q]);
        o2[j] = (bf16)(b * c2a[q] + a * s2a[q]);
    }
    *(bf16x8*)(p + d0)      = o1;
    *(bf16x8*)(p + d0 + 64) = o2;
}

// ---------------------------------------------------------------------------
// Flash attention (causal, GQA 4:1), 4 waves x 16 q-rows, KV tile 64.
// ---------------------------------------------------------------------------
__global__ __launch_bounds__(256)
void attn_k(const bf16* __restrict__ Q,   // [32][1024][128]
            const bf16* __restrict__ Kb,  // [8][1024][128]
            const bf16* __restrict__ Vt,  // [8][128][1024]
            bf16* __restrict__ O)         // [1024][4096]
{
    const int T = 1024;
    __shared__ __align__(16) bf16 Ks[64][128];
    __shared__ __align__(16) bf16 Vs[128][64];
    __shared__ __align__(16) bf16 Ps[4][16][72];

    const int qt = blockIdx.x, h = blockIdx.y, hk = h >> 2;
    const int tid = threadIdx.x, lane = tid & 63, w = tid >> 6;
    const int g = lane >> 4, r = lane & 15;
    const int qrow0 = qt * 64 + w * 16;

    bf16x8 qf[4];
    const bf16* qp = Q + ((long)h * T + qrow0 + r) * 128;
    #pragma unroll
    for (int dc = 0; dc < 4; dc++) qf[dc] = *(const bf16x8*)(qp + dc * 32 + g * 8);

    f32x4 o_acc[8] = {};
    float m_run[4], l_run[4];
    #pragma unroll
    for (int j = 0; j < 4; j++) { m_run[j] = -1e30f; l_run[j] = 0.f; }

    const float scale = 0.08838834764831845f;
    const int kv_end = qt * 64 + 64;

    for (int kv0 = 0; kv0 < kv_end; kv0 += 64) {
        __syncthreads();
        {
            int tr = tid >> 2;
            const bf16* src = Kb + ((long)hk * T + kv0 + tr) * 128;
            #pragma unroll
            for (int q4 = 0; q4 < 4; q4++) {
                int c = (tid & 3) * 4 + q4;
                bf16x8 v = *(const bf16x8*)(src + c * 8);
                *(bf16x8*)&Ks[tr][(c ^ (tr & 7)) * 8] = v;
            }
        }
        {
            int dd = tid >> 1;
            const bf16* src = Vt + ((long)hk * 128 + dd) * T + kv0;
            #pragma unroll
            for (int q4 = 0; q4 < 4; q4++) {
                int c = (tid & 1) * 4 + q4;
                bf16x8 v = *(const bf16x8*)(src + c * 8);
                *(bf16x8*)&Vs[dd][(c ^ (dd & 7)) * 8] = v;
            }
        }
        __syncthreads();

        f32x4 s[4] = {};
        #pragma unroll
        for (int n = 0; n < 4; n++) {
            int tr = n * 16 + r;
            #pragma unroll
            for (int dc = 0; dc < 4; dc++) {
                int c = (dc * 4 + g) ^ (tr & 7);
                bf16x8 kf = *(const bf16x8*)&Ks[tr][c * 8];
                s[n] = __builtin_amdgcn_mfma_f32_16x16x32_bf16(qf[dc], kf, s[n], 0, 0, 0);
            }
        }

        #pragma unroll
        for (int j = 0; j < 4; j++) {
            int qpos = qrow0 + g * 4 + j;
            float mx = m_run[j];
            #pragma unroll
            for (int n = 0; n < 4; n++) {
                int kpos = kv0 + n * 16 + r;
                float sv = s[n][j] * scale;
                sv = (kpos <= qpos) ? sv : -1e30f;
                s[n][j] = sv;
                mx = fmaxf(mx, sv);
            }
            #pragma unroll
            for (int mask = 1; mask < 16; mask <<= 1) mx = fmaxf(mx, __shfl_xor(mx, mask));
            float corr = __expf(m_run[j] - mx);
            l_run[j] *= corr;
            #pragma unroll
            for (int db = 0; db < 8; db++) o_acc[db][j] *= corr;
            float ls = 0.f;
            #pragma unroll
            for (int n = 0; n < 4; n++) {
                float p = __expf(s[n][j] - mx);
                s[n][j] = p;
                ls += p;
            }
            #pragma unroll
            for (int mask = 1; mask < 16; mask <<= 1) ls += __shfl_xor(ls, mask);
            l_run[j] += ls;
            m_run[j] = mx;
        }

        #pragma unroll
        for (int n = 0; n < 4; n++)
            #pragma unroll
            for (int j = 0; j < 4; j++)
                Ps[w][g * 4 + j][n * 16 + r] = (bf16)s[n][j];
        __syncthreads();

        bf16x8 pf[2];
        #pragma unroll
        for (int kc = 0; kc < 2; kc++)
            pf[kc] = *(const bf16x8*)&Ps[w][r][kc * 32 + g * 8];
        #pragma unroll
        for (int db = 0; db < 8; db++) {
            #pragma unroll
            for (int kc = 0; kc < 2; kc++) {
                int dd = db * 16 + r;
                int c = (kc * 4 + g) ^ (dd & 7);
                bf16x8 vf = *(const bf16x8*)&Vs[dd][c * 8];
                o_acc[db] = __builtin_amdgcn_mfma_f32_16x16x32_bf16(pf[kc], vf, o_acc[db], 0, 0, 0);
            }
        }
    }

    #pragma unroll
    for (int db = 0; db < 8; db++) {
        #pragma unroll
        for (int j = 0; j < 4; j++) {
            int t = qrow0 + g * 4 + j;
            float v = o_acc[db][j] / l_run[j];
            O[(long)t * 4096 + h * 128 + db * 16 + r] = (bf16)v;
        }
    }
}

// ---------------------------------------------------------------------------
extern "C" void kernel_launch(void* const* d_in, const int* in_sizes, int n_in,
                              void* d_out, int out_size, void* d_ws, size_t ws_size,
                              hipStream_t stream)
{
    const float* X   = (const float*)d_in[0];
    const float* LN1 = (const float*)d_in[1];
    const float* LN2 = (const float*)d_in[2];
    const float* qUs = (const float*)d_in[3];
    const float* qV  = (const float*)d_in[4];
    const float* kUs = (const float*)d_in[5];
    const float* kV  = (const float*)d_in[6];
    const float* vUs = (const float*)d_in[7];
    const float* vV  = (const float*)d_in[8];
    const float* oUs = (const float*)d_in[9];
    const float* oV  = (const float*)d_in[10];
    const float* gUs = (const float*)d_in[11];
    const float* gV  = (const float*)d_in[12];
    const float* uUs = (const float*)d_in[13];
    const float* uV  = (const float*)d_in[14];
    const float* dUs = (const float*)d_in[15];
    const float* dV  = (const float*)d_in[16];
    float* OUT = (float*)d_out;

    char* w = (char*)d_ws;
    bf16*  h1   = (bf16*)(w + 0);          // [1024,4096]
    bf16*  xrq  = (bf16*)(w + 8388608);    // [1024,2048]
    bf16*  xrk  = (bf16*)(w + 12582912);   // [1024,512]
    bf16*  xrv  = (bf16*)(w + 13631488);   // [1024,512]
    bf16*  qb   = (bf16*)(w + 14680064);   // [32,1024,128]
    bf16*  kb   = (bf16*)(w + 23068672);   // [8,1024,128]
    bf16*  vt   = (bf16*)(w + 25165824);   // [8,128,1024]
    float* cs   = (float*)(w + 27262976);  // [1024,64]
    float* sn   = (float*)(w + 27525120);  // [1024,64]
    bf16*  att  = (bf16*)(w + 27787264);   // [1024,4096]
    bf16*  r1   = (bf16*)(w + 36175872);   // [1024,1024]
    bf16*  h2   = (bf16*)(w + 0);
    bf16*  gr   = (bf16*)(w + 8388608);
    bf16*  ur   = (bf16*)(w + 10485760);
    bf16*  hmid = (bf16*)(w + 12582912);   // [1024,14336]
    bf16*  dr   = (bf16*)(w + 41943040);   // [1024,1024]
    const size_t ARENA  = 44040192;
    const size_t PARTSZ = 134217728;       // 128 MB partial arena
    float* part = (float*)(w + ARENA);
    const bool med = ws_size >= ARENA + PARTSZ;

    dim3 blk(256), blk8(512);

    if (med) {
        rmsnorm_k<<<1024, blk, 0, stream>>>(X, LN1, h1);
        // xr_q: K=4096 split 8 -> 1024 blocks (K=512, nt=8); planes 8x8MB
        gemm8w<EPI_PART><<<dim3(128,1,8), blk8, 0, stream>>>(h1,4096,0, qV,4096,0,nullptr, part,2048,2097152, nullptr, 512,8, 8);
        reduce_k<<<2048, blk, 0, stream>>>(part, 2097152, 8, xrq);
        // xr_k + xr_v batched (share A=h1), split 8 each -> 512 blocks
        gemm8w<EPI_PART><<<dim3(32,1,16), blk8, 0, stream>>>(h1,4096,0, kV,4096,0,vV, part,512,524288, nullptr, 512,8, 8);
        reduce_k<<<512, blk, 0, stream>>>(part,             524288, 8, xrk);
        reduce_k<<<512, blk, 0, stream>>>(part + 8L*524288, 524288, 8, xrv);

        gemm8w<EPI_BF16 ><<<dim3(8,1,32), blk8, 0, stream>>>(xrq,2048,64, qUs,64,8192,nullptr, qb,128,131072, nullptr, 64,1, 8);
        gemm8w<EPI_BF16 ><<<dim3(8,1, 8), blk8, 0, stream>>>(xrk, 512,64, kUs,64,8192,nullptr, kb,128,131072, nullptr, 64,1, 8);
        gemm8w<EPI_BF16T><<<dim3(8,1, 8), blk8, 0, stream>>>(xrv, 512,64, vUs,64,8192,nullptr, vt,1024,131072, nullptr, 64,1, 8);
        rope_table_k<<<256, blk, 0, stream>>>(cs, sn);
        rope_k<<<1024, blk, 0, stream>>>(qb, cs, sn);
        rope_k<<< 256, blk, 0, stream>>>(kb, cs, sn);
        attn_k<<<dim3(16,32), blk, 0, stream>>>(qb, kb, vt, att);

        // attn @ oV^T: K=4096 split 8 -> 512 blocks (K=512, nt=8)
        gemm8w<EPI_PART><<<dim3(64,1,8), blk8, 0, stream>>>(att,4096,0, oV,4096,0,nullptr, part,1024,1048576, nullptr, 512,8, 8);
        reduce_k<<<1024, blk, 0, stream>>>(part, 1048576, 8, r1);
        // oUs: K=1024 split 2 -> 512 blocks; reduce_addf adds X residual
        gemm8w<EPI_PART><<<dim3(256,1,2), blk8, 0, stream>>>(r1,1024,0, oUs,1024,0,nullptr, part,4096,4194304, nullptr, 512,2, 8);
        reduce_addf<<<4096, blk, 0, stream>>>(part, 4194304, 2, X, OUT);

        rmsnorm_k<<<1024, blk, 0, stream>>>(OUT, LN2, h2);
        // gV + uV batched, split 8 each -> 1024 blocks
        gemm8w<EPI_PART><<<dim3(64,1,16), blk8, 0, stream>>>(h2,4096,0, gV,4096,0,uV, part,1024,1048576, nullptr, 512,8, 8);
        reduce_k<<<1024, blk, 0, stream>>>(part,              1048576, 8, gr);
        reduce_k<<<1024, blk, 0, stream>>>(part + 8L*1048576, 1048576, 8, ur);
        gemm8w<EPI_SILU1><<<dim3(896,1,1), blk8, 0, stream>>>(gr,1024,0, gUs,1024,0,nullptr, hmid,14336,0, nullptr, 1024,1, 8);
        gemm8w<EPI_MUL  ><<<dim3(896,1,1), blk8, 0, stream>>>(ur,1024,0, uUs,1024,0,nullptr, hmid,14336,0, nullptr, 1024,1, 8);
        // dV: K=14336 split 14 -> 896 blocks (K=1024, nt=16)
        gemm8w<EPI_PART ><<<dim3(64,1,14), blk8, 0, stream>>>(hmid,14336,0, dV,14336,0,nullptr, part,1024,1048576, nullptr, 1024,14, 8);
        reduce_k<<<1024, blk, 0, stream>>>(part, 1048576, 14, dr);
        // dUs: K=1024 split 2 -> 512 blocks; reduce_addf adds OUT residual
        gemm8w<EPI_PART><<<dim3(256,1,2), blk8, 0, stream>>>(dr,1024,0, dUs,1024,0,nullptr, part,4096,4194304, nullptr, 512,2, 8);
        reduce_addf<<<4096, blk, 0, stream>>>(part, 4194304, 2, OUT, OUT);
        return;
    }

    // ---------------- fallback: gemm2 (fp32-B dbuf) path ----------------
    rmsnorm_k<<<1024, blk, 0, stream>>>(X, LN1, h1);
    gemm2<EPI_BF16><<<dim3(8,16,1), blk, 0, stream>>>(h1,4096,0, qV,4096,0,nullptr, xrq,2048,0, nullptr, 4096, 1);
    gemm2<EPI_BF16><<<dim3(8, 4,1), blk, 0, stream>>>(h1,4096,0, kV,4096,0,nullptr, xrk, 512,0, nullptr, 4096, 1);
    gemm2<EPI_BF16><<<dim3(8, 4,1), blk, 0, stream>>>(h1,4096,0, vV,4096,0,nullptr, xrv, 512,0, nullptr, 4096, 1);
    gemm2<EPI_BF16 ><<<dim3(8,1,32), blk, 0, stream>>>(xrq,2048,64, qUs,64,8192,nullptr, qb,128,131072, nullptr, 64, 1);
    gemm2<EPI_BF16 ><<<dim3(8,1, 8), blk, 0, stream>>>(xrk, 512,64, kUs,64,8192,nullptr, kb,128,131072, nullptr, 64, 1);
    gemm2<EPI_BF16T><<<dim3(8,1, 8), blk, 0, stream>>>(xrv, 512,64, vUs,64,8192,nullptr, vt,1024,131072, nullptr, 64, 1);
    rope_table_k<<<256, blk, 0, stream>>>(cs, sn);
    rope_k<<<1024, blk, 0, stream>>>(qb, cs, sn);
    rope_k<<< 256, blk, 0, stream>>>(kb, cs, sn);
    attn_k<<<dim3(16,32), blk, 0, stream>>>(qb, kb, vt, att);
    gemm2<EPI_BF16><<<dim3(8,8,1), blk, 0, stream>>>(att,4096,0, oV,4096,0,nullptr, r1,1024,0, nullptr, 4096, 1);
    gemm2<EPI_F32ADD><<<dim3(8,32,1), blk, 0, stream>>>(r1,1024,0, oUs,1024,0,nullptr, OUT,4096,0, X, 1024, 1);
    rmsnorm_k<<<1024, blk, 0, stream>>>(OUT, LN2, h2);
    gemm2<EPI_BF16><<<dim3(8,8,1), blk, 0, stream>>>(h2,4096,0, gV,4096,0,nullptr, gr,1024,0, nullptr, 4096, 1);
    gemm2<EPI_BF16><<<dim3(8,8,1), blk, 0, stream>>>(h2,4096,0, uV,4096,0,nullptr, ur,1024,0, nullptr, 4096, 1);
    gemm2<EPI_SILU1><<<dim3(8,112,1), blk, 0, stream>>>(gr,1024,0, gUs,1024,0,nullptr, hmid,14336,0, nullptr, 1024, 1);
    gemm2<EPI_MUL  ><<<dim3(8,112,1), blk, 0, stream>>>(ur,1024,0, uUs,1024,0,nullptr, hmid,14336,0, nullptr, 1024, 1);
    gemm2<EPI_BF16><<<dim3(8,8,1), blk, 0, stream>>>(hmid,14336,0, dV,14336,0,nullptr, dr,1024,0, nullptr, 14336, 1);
    gemm2<EPI_F32ADD><<<dim3(8,32,1), blk, 0, stream>>>(dr,1024,0, dUs,1024,0,nullptr, OUT,4096,0, OUT, 1024, 1);
}

// Round 15
// 507.230 us; speedup vs baseline: 1.0465x; 1.0465x over previous
//
#include <hip/hip_runtime.h>
#include <math.h>

// ---------------------------------------------------------------------------
// FlashSVD LLaMA block, round 15: round-12 VERBATIM (best passing config,
// 507us). r14's fused SILU*MUL kernel was 10us faster but showed replay
// nondeterminism (post-timing absmax 3.8) — unexplained race, reverted per
// rigor discipline. gemm8w = 8-wave 128x128/BK=64, 48KB single-buffered LDS,
// 3 blk/CU = 24 waves/CU, conflict-free XOR swizzles, global_load_lds both
// operands, XCD-bijective block remap, split-K fp32 partials + reduce.
// ---------------------------------------------------------------------------

typedef __bf16 bf16;
typedef __bf16 bf16x8 __attribute__((ext_vector_type(8)));
typedef __bf16 bf16x4 __attribute__((ext_vector_type(4)));
typedef float  f32x4  __attribute__((ext_vector_type(4)));

#define EPI_BF16   0
#define EPI_BF16T  1   // transposed bf16 store (V in [d][t] layout)
#define EPI_F32ADD 2   // fp32 store with residual add
#define EPI_SILU1  3   // store silu(acc) bf16
#define EPI_MUL    4   // RMW: C *= acc (bf16)
#define EPI_PART   5   // fp32 partial plane store (split-K)

__device__ __forceinline__ void gld16(const void* g, void* l) {
    __builtin_amdgcn_global_load_lds(
        (const __attribute__((address_space(1))) unsigned int*)g,
        (__attribute__((address_space(3))) unsigned int*)l, 16, 0, 0);
}

// ---------------------------------------------------------------------------
// gemm8w: A bf16 [M,K], B fp32 [N,K], 128x128 tile, BK=64, 8 waves (2M x 4N,
// wave tile 64x32), single-buffered 48KB LDS -> 3 blk/CU = 24 waves/CU,
// 2 barriers/K-step, both operands via global_load_lds, source pre-swizzled
// (A: chunk8 ^= row&7; B: chunk16 ^= row&15), matching XOR on reads.
// Grid: dim3(nwg,1,z); XCD-bijective remap; bm=id%gx, bn=id/gx.
// grid.z = batch*nsplit; zb selects B2 when given (two GEMMs sharing A).
// ---------------------------------------------------------------------------
template<int EPI>
__global__ __launch_bounds__(512)
void gemm8w(const bf16* __restrict__ A, int lda, long sA,
            const float* __restrict__ B, int ldb, long sB, const float* __restrict__ B2,
            void* __restrict__ Cv, int ldc, long sC,
            const float* __restrict__ R, int Kc, int nsplit, int gx)
{
    __shared__ __align__(16) bf16  As[128 * 64];   // 16 KB
    __shared__ __align__(16) float Bs[128 * 64];   // 32 KB

    const int tid = threadIdx.x, lane = tid & 63, w = tid >> 6;  // 8 waves
    const int wr = w >> 2, wcn = w & 3;            // 2M x 4N, wave tile 64x32

    int id = blockIdx.x;
    {   // bijective XCD remap (m204)
        const int nwg = gridDim.x;
        int q = nwg >> 3, rr = nwg & 7;
        int xcd = id & 7, off = id >> 3;
        id = (xcd < rr ? xcd * (q + 1) : rr * (q + 1) + (xcd - rr) * q) + off;
    }
    const int bm = id % gx, bn = id / gx, bz = blockIdx.z;
    const int ks = bz % nsplit, zb = bz / nsplit;

    const float* Bp = (B2 != nullptr && zb != 0) ? B2 : B;
    const bf16*  Ab = A  + (long)zb * sA + (long)(bm * 128) * lda + (long)ks * Kc;
    const float* Bb = Bp + (long)zb * sB + (long)(bn * 128) * ldb + (long)ks * Kc;

    const int g = lane >> 4, r = lane & 15;
    f32x4 acc[4][2] = {};
    const int nt = Kc >> 6;

    for (int t = 0; t < nt; t++) {
        if (t) __syncthreads();
        const bf16*  At = Ab + t * 64;
        const float* Bt = Bb + t * 64;
        // A: 1024 16B-chunks (8/row); slot ci holds global chunk (ci&7)^(row&7)
        #pragma unroll
        for (int i = 0; i < 2; i++) {
            int cb = w * 128 + i * 64, ci = cb + lane;
            int row = ci >> 3, col = ((ci & 7) ^ (row & 7)) * 8;
            gld16(At + (long)row * lda + col, &As[cb * 8]);
        }
        // B: 2048 16B-chunks (16/row); slot ci holds global chunk (ci&15)^(row&15)
        #pragma unroll
        for (int i = 0; i < 4; i++) {
            int cb = w * 256 + i * 64, ci = cb + lane;
            int row = ci >> 4, col = ((ci & 15) ^ (row & 15)) * 4;
            gld16(Bt + (long)row * ldb + col, &Bs[cb * 4]);
        }
        __syncthreads();
        #pragma unroll
        for (int kk = 0; kk < 2; kk++) {
            bf16x8 af[4], bfr[2];
            #pragma unroll
            for (int m = 0; m < 4; m++) {
                int row = wr * 64 + m * 16 + r;
                af[m] = *(const bf16x8*)&As[row * 64 + (((kk * 4 + g) ^ (row & 7)) * 8)];
            }
            #pragma unroll
            for (int n = 0; n < 2; n++) {
                int row = wcn * 32 + n * 16 + r;
                int c0 = kk * 8 + g * 2;
                f32x4 lo = *(const f32x4*)&Bs[row * 64 + (((c0    ) ^ (row & 15)) * 4)];
                f32x4 hi = *(const f32x4*)&Bs[row * 64 + (((c0 + 1) ^ (row & 15)) * 4)];
                bfr[n] = bf16x8{(bf16)lo[0], (bf16)lo[1], (bf16)lo[2], (bf16)lo[3],
                                (bf16)hi[0], (bf16)hi[1], (bf16)hi[2], (bf16)hi[3]};
            }
            #pragma unroll
            for (int m = 0; m < 4; m++)
                #pragma unroll
                for (int n = 0; n < 2; n++)
                    acc[m][n] = __builtin_amdgcn_mfma_f32_16x16x32_bf16(af[m], bfr[n], acc[m][n], 0, 0, 0);
        }
    }

    // epilogue: C layout col = lane&15, row = (lane>>4)*4 + j
    #pragma unroll
    for (int m = 0; m < 4; m++) {
        #pragma unroll
        for (int n = 0; n < 2; n++) {
            const int row0 = bm * 128 + wr * 64 + m * 16 + g * 4;
            const int col  = bn * 128 + wcn * 32 + n * 16 + r;
            #pragma unroll
            for (int j = 0; j < 4; j++) {
                float v = acc[m][n][j];
                long row = row0 + j;
                if constexpr (EPI == EPI_BF16) {
                    ((bf16*)Cv)[(long)zb * sC + row * (long)ldc + col] = (bf16)v;
                } else if constexpr (EPI == EPI_BF16T) {
                    ((bf16*)Cv)[(long)zb * sC + (long)col * ldc + row] = (bf16)v;
                } else if constexpr (EPI == EPI_F32ADD) {
                    long idx = row * (long)ldc + col;
                    ((float*)Cv)[idx] = v + R[idx];
                } else if constexpr (EPI == EPI_PART) {
                    ((float*)Cv)[(long)bz * sC + row * (long)ldc + col] = v;
                } else if constexpr (EPI == EPI_SILU1) {
                    ((bf16*)Cv)[row * (long)ldc + col] = (bf16)(v / (1.f + __expf(-v)));
                } else { // EPI_MUL
                    bf16* p = &((bf16*)Cv)[row * (long)ldc + col];
                    *p = (bf16)((float)*p * v);
                }
            }
        }
    }
}

// ---------------------------------------------------------------------------
// gemm2 (fallback for small workspace): fp32 B converted in staging, dbuf.
// ---------------------------------------------------------------------------
template<int EPI>
__global__ __launch_bounds__(256)
void gemm2(const bf16* __restrict__ A, int lda, long sA,
           const float* __restrict__ B, int ldb, long sB, const float* __restrict__ B2,
           void* __restrict__ Cv, int ldc, long sC,
           const float* __restrict__ R, int Kc, int nsplit)
{
    __shared__ __align__(16) bf16 As[2][128 * 64];
    __shared__ __align__(16) bf16 Bs[2][128 * 64];

    const int tid = threadIdx.x, lane = tid & 63, w = tid >> 6;
    const int wr = w >> 1, wc = w & 1;
    const int bm = blockIdx.x, bn = blockIdx.y, bz = blockIdx.z;
    const int ks = bz % nsplit, zb = bz / nsplit;

    const float* Bp = (B2 != nullptr && zb != 0) ? B2 : B;
    const bf16*  Ab = A  + (long)zb * sA + (long)(bm * 128) * lda + (long)ks * Kc;
    const float* Bb = Bp + (long)zb * sB + (long)(bn * 128) * ldb + (long)ks * Kc;

    const int g = lane >> 4, r = lane & 15;
    f32x4 acc[4][4] = {};
    const int nt = Kc >> 6;
    int cur = 0;

    {
        #pragma unroll
        for (int i = 0; i < 4; i++) {
            int cb = i * 256 + w * 64, ci = cb + lane;
            int arow = ci >> 3, acol = ((ci & 7) ^ (arow & 7)) * 8;
            gld16(Ab + (long)arow * lda + acol, &As[0][cb * 8]);
        }
        float4 fb[8];
        #pragma unroll
        for (int i = 0; i < 8; i++) {
            int p = i * 256 + tid;
            fb[i] = *(const float4*)(Bb + (long)(p >> 4) * ldb + (p & 15) * 4);
        }
        #pragma unroll
        for (int i = 0; i < 8; i++) {
            int p = i * 256 + tid, brow = p >> 4, c4 = p & 15;
            bf16x4 h = {(bf16)fb[i].x, (bf16)fb[i].y, (bf16)fb[i].z, (bf16)fb[i].w};
            *(bf16x4*)&Bs[0][brow * 64 + (((c4 >> 1) ^ (brow & 7)) * 8) + (c4 & 1) * 4] = h;
        }
    }
    __syncthreads();

    for (int t = 0; t < nt; t++) {
        float4 fb[8];
        if (t + 1 < nt) {
            const bf16* An = Ab + (t + 1) * 64;
            #pragma unroll
            for (int i = 0; i < 4; i++) {
                int cb = i * 256 + w * 64, ci = cb + lane;
                int arow = ci >> 3, acol = ((ci & 7) ^ (arow & 7)) * 8;
                gld16(An + (long)arow * lda + acol, &As[cur ^ 1][cb * 8]);
            }
            const float* Bn = Bb + (t + 1) * 64;
            #pragma unroll
            for (int i = 0; i < 8; i++) {
                int p = i * 256 + tid;
                fb[i] = *(const float4*)(Bn + (long)(p >> 4) * ldb + (p & 15) * 4);
            }
        }
        #pragma unroll
        for (int kk = 0; kk < 2; kk++) {
            bf16x8 af[4], bfr[4];
            #pragma unroll
            for (int m = 0; m < 4; m++) {
                int row = wr * 64 + m * 16 + r;
                af[m] = *(const bf16x8*)&As[cur][row * 64 + (((kk * 4 + g) ^ (row & 7)) * 8)];
            }
            #pragma unroll
            for (int n = 0; n < 4; n++) {
                int row = wc * 64 + n * 16 + r;
                bfr[n] = *(const bf16x8*)&Bs[cur][row * 64 + (((kk * 4 + g) ^ (row & 7)) * 8)];
            }
            #pragma unroll
            for (int m = 0; m < 4; m++)
                #pragma unroll
                for (int n = 0; n < 4; n++)
                    acc[m][n] = __builtin_amdgcn_mfma_f32_16x16x32_bf16(af[m], bfr[n], acc[m][n], 0, 0, 0);
        }
        if (t + 1 < nt) {
            #pragma unroll
            for (int i = 0; i < 8; i++) {
                int p = i * 256 + tid, brow = p >> 4, c4 = p & 15;
                bf16x4 h = {(bf16)fb[i].x, (bf16)fb[i].y, (bf16)fb[i].z, (bf16)fb[i].w};
                *(bf16x4*)&Bs[cur ^ 1][brow * 64 + (((c4 >> 1) ^ (brow & 7)) * 8) + (c4 & 1) * 4] = h;
            }
            __syncthreads();
            cur ^= 1;
        }
    }

    #pragma unroll
    for (int m = 0; m < 4; m++) {
        #pragma unroll
        for (int n = 0; n < 4; n++) {
            const int row0 = bm * 128 + wr * 64 + m * 16 + g * 4;
            const int col  = bn * 128 + wc * 64 + n * 16 + r;
            #pragma unroll
            for (int j = 0; j < 4; j++) {
                float v = acc[m][n][j];
                long row = row0 + j;
                if constexpr (EPI == EPI_BF16) {
                    ((bf16*)Cv)[(long)zb * sC + row * (long)ldc + col] = (bf16)v;
                } else if constexpr (EPI == EPI_BF16T) {
                    ((bf16*)Cv)[(long)zb * sC + (long)col * ldc + row] = (bf16)v;
                } else if constexpr (EPI == EPI_F32ADD) {
                    long idx = row * (long)ldc + col;
                    ((float*)Cv)[idx] = v + R[idx];
                } else if constexpr (EPI == EPI_PART) {
                    ((float*)Cv)[(long)bz * sC + row * (long)ldc + col] = v;
                } else if constexpr (EPI == EPI_SILU1) {
                    ((bf16*)Cv)[row * (long)ldc + col] = (bf16)(v / (1.f + __expf(-v)));
                } else {
                    bf16* p = &((bf16*)Cv)[row * (long)ldc + col];
                    *p = (bf16)((float)*p * v);
                }
            }
        }
    }
}

// ---------------------------------------------------------------------------
__global__ __launch_bounds__(256)
void reduce_k(const float* __restrict__ part, long pe, int np, bf16* __restrict__ out)
{
    long i = ((long)blockIdx.x * 256 + threadIdx.x) * 4;
    float4 s = *(const float4*)&part[i];
    for (int p = 1; p < np; p++) {
        float4 v = *(const float4*)&part[(long)p * pe + i];
        s.x += v.x; s.y += v.y; s.z += v.z; s.w += v.w;
    }
    bf16x4 o = {(bf16)s.x, (bf16)s.y, (bf16)s.z, (bf16)s.w};
    *(bf16x4*)&out[i] = o;
}

__global__ __launch_bounds__(256)
void rmsnorm_k(const float* __restrict__ x, const float* __restrict__ w,
               bf16* __restrict__ out)
{
    const int D = 4096;
    const long row = blockIdx.x;
    const float* xr = x + row * D;
    float4 v[4];
    float ss = 0.f;
    #pragma unroll
    for (int k = 0; k < 4; k++) {
        v[k] = *(const float4*)&xr[threadIdx.x * 4 + k * 1024];
        ss += v[k].x * v[k].x + v[k].y * v[k].y + v[k].z * v[k].z + v[k].w * v[k].w;
    }
    #pragma unroll
    for (int o = 32; o > 0; o >>= 1) ss += __shfl_down(ss, o);
    __shared__ float red[4];
    if ((threadIdx.x & 63) == 0) red[threadIdx.x >> 6] = ss;
    __syncthreads();
    float rs = rsqrtf((red[0] + red[1] + red[2] + red[3]) / D + 1e-5f);
    #pragma unroll
    for (int k = 0; k < 4; k++) {
        int i = threadIdx.x * 4 + k * 1024;
        float4 wv = *(const float4*)&w[i];
        bf16x4 o4 = {(bf16)(v[k].x * rs * wv.x), (bf16)(v[k].y * rs * wv.y),
                     (bf16)(v[k].z * rs * wv.z), (bf16)(v[k].w * rs * wv.w)};
        *(bf16x4*)&out[row * D + i] = o4;
    }
}

__global__ __launch_bounds__(256)
void rope_table_k(float* cs, float* sn)
{
    int idx = blockIdx.x * blockDim.x + threadIdx.x;  // 1024*64
    int t = idx >> 6, i = idx & 63;
    float inv = powf(10000.0f, -(2.0f * i) / 128.0f);
    float a = (float)t * inv;
    cs[idx] = cosf(a);
    sn[idx] = sinf(a);
}

// rope, vectorized: each thread owns 8 d-pairs (16B loads/stores).
__global__ __launch_bounds__(256)
void rope_k(bf16* qk, const float* __restrict__ cs, const float* __restrict__ sn)
{
    long idx = (long)blockIdx.x * blockDim.x + threadIdx.x;  // nh*1024*8
    int d0 = (int)(idx & 7) * 8;          // 0,8,..,56
    long ht = idx >> 3;
    int t = (int)(ht & 1023);
    bf16* p = qk + ht * 128;
    bf16x8 x1 = *(const bf16x8*)(p + d0);
    bf16x8 x2 = *(const bf16x8*)(p + d0 + 64);
    int i0 = d0 >> 1;                      // 4 angle idxs, each used twice
    float4 c1 = *(const float4*)&cs[t * 64 + i0];
    float4 s1 = *(const float4*)&sn[t * 64 + i0];
    float4 c2 = *(const float4*)&cs[t * 64 + 32 + i0];
    float4 s2 = *(const float4*)&sn[t * 64 + 32 + i0];
    float c1a[4] = {c1.x, c1.y, c1.z, c1.w}, s1a[4] = {s1.x, s1.y, s1.z, s1.w};
    float c2a[4] = {c2.x, c2.y, c2.z, c2.w}, s2a[4] = {s2.x, s2.y, s2.z, s2.w};
    bf16x8 o1, o2;
    #pragma unroll
    for (int j = 0; j < 8; j++) {
        float a = (float)x1[j], b = (float)x2[j];
        int q = j >> 1;
        o1[j] = (bf16)(a * c1a[q] - b * s1a[q]);
        o2[j] = (bf16)(b * c2a[q] + a * s2a[q]);
    }
    *(bf16x8*)(p + d0)      = o1;
    *(bf16x8*)(p + d0 + 64) = o2;
}

// ---------------------------------------------------------------------------
// Flash attention (causal, GQA 4:1), 4 waves x 16 q-rows, KV tile 64.
// ---------------------------------------------------------------------------
__global__ __launch_bounds__(256)
void attn_k(const bf16* __restrict__ Q,   // [32][1024][128]
            const bf16* __restrict__ Kb,  // [8][1024][128]
            const bf16* __restrict__ Vt,  // [8][128][1024]
            bf16* __restrict__ O)         // [1024][4096]
{
    const int T = 1024;
    __shared__ __align__(16) bf16 Ks[64][128];
    __shared__ __align__(16) bf16 Vs[128][64];
    __shared__ __align__(16) bf16 Ps[4][16][72];

    const int qt = blockIdx.x, h = blockIdx.y, hk = h >> 2;
    const int tid = threadIdx.x, lane = tid & 63, w = tid >> 6;
    const int g = lane >> 4, r = lane & 15;
    const int qrow0 = qt * 64 + w * 16;

    bf16x8 qf[4];
    const bf16* qp = Q + ((long)h * T + qrow0 + r) * 128;
    #pragma unroll
    for (int dc = 0; dc < 4; dc++) qf[dc] = *(const bf16x8*)(qp + dc * 32 + g * 8);

    f32x4 o_acc[8] = {};
    float m_run[4], l_run[4];
    #pragma unroll
    for (int j = 0; j < 4; j++) { m_run[j] = -1e30f; l_run[j] = 0.f; }

    const float scale = 0.08838834764831845f;
    const int kv_end = qt * 64 + 64;

    for (int kv0 = 0; kv0 < kv_end; kv0 += 64) {
        __syncthreads();
        {
            int tr = tid >> 2;
            const bf16* src = Kb + ((long)hk * T + kv0 + tr) * 128;
            #pragma unroll
            for (int q4 = 0; q4 < 4; q4++) {
                int c = (tid & 3) * 4 + q4;
                bf16x8 v = *(const bf16x8*)(src + c * 8);
                *(bf16x8*)&Ks[tr][(c ^ (tr & 7)) * 8] = v;
            }
        }
        {
            int dd = tid >> 1;
            const bf16* src = Vt + ((long)hk * 128 + dd) * T + kv0;
            #pragma unroll
            for (int q4 = 0; q4 < 4; q4++) {
                int c = (tid & 1) * 4 + q4;
                bf16x8 v = *(const bf16x8*)(src + c * 8);
                *(bf16x8*)&Vs[dd][(c ^ (dd & 7)) * 8] = v;
            }
        }
        __syncthreads();

        f32x4 s[4] = {};
        #pragma unroll
        for (int n = 0; n < 4; n++) {
            int tr = n * 16 + r;
            #pragma unroll
            for (int dc = 0; dc < 4; dc++) {
                int c = (dc * 4 + g) ^ (tr & 7);
                bf16x8 kf = *(const bf16x8*)&Ks[tr][c * 8];
                s[n] = __builtin_amdgcn_mfma_f32_16x16x32_bf16(qf[dc], kf, s[n], 0, 0, 0);
            }
        }

        #pragma unroll
        for (int j = 0; j < 4; j++) {
            int qpos = qrow0 + g * 4 + j;
            float mx = m_run[j];
            #pragma unroll
            for (int n = 0; n < 4; n++) {
                int kpos = kv0 + n * 16 + r;
                float sv = s[n][j] * scale;
                sv = (kpos <= qpos) ? sv : -1e30f;
                s[n][j] = sv;
                mx = fmaxf(mx, sv);
            }
            #pragma unroll
            for (int mask = 1; mask < 16; mask <<= 1) mx = fmaxf(mx, __shfl_xor(mx, mask));
            float corr = __expf(m_run[j] - mx);
            l_run[j] *= corr;
            #pragma unroll
            for (int db = 0; db < 8; db++) o_acc[db][j] *= corr;
            float ls = 0.f;
            #pragma unroll
            for (int n = 0; n < 4; n++) {
                float p = __expf(s[n][j] - mx);
                s[n][j] = p;
                ls += p;
            }
            #pragma unroll
            for (int mask = 1; mask < 16; mask <<= 1) ls += __shfl_xor(ls, mask);
            l_run[j] += ls;
            m_run[j] = mx;
        }

        #pragma unroll
        for (int n = 0; n < 4; n++)
            #pragma unroll
            for (int j = 0; j < 4; j++)
                Ps[w][g * 4 + j][n * 16 + r] = (bf16)s[n][j];
        __syncthreads();

        bf16x8 pf[2];
        #pragma unroll
        for (int kc = 0; kc < 2; kc++)
            pf[kc] = *(const bf16x8*)&Ps[w][r][kc * 32 + g * 8];
        #pragma unroll
        for (int db = 0; db < 8; db++) {
            #pragma unroll
            for (int kc = 0; kc < 2; kc++) {
                int dd = db * 16 + r;
                int c = (kc * 4 + g) ^ (dd & 7);
                bf16x8 vf = *(const bf16x8*)&Vs[dd][c * 8];
                o_acc[db] = __builtin_amdgcn_mfma_f32_16x16x32_bf16(pf[kc], vf, o_acc[db], 0, 0, 0);
            }
        }
    }

    #pragma unroll
    for (int db = 0; db < 8; db++) {
        #pragma unroll
        for (int j = 0; j < 4; j++) {
            int t = qrow0 + g * 4 + j;
            float v = o_acc[db][j] / l_run[j];
            O[(long)t * 4096 + h * 128 + db * 16 + r] = (bf16)v;
        }
    }
}

// ---------------------------------------------------------------------------
extern "C" void kernel_launch(void* const* d_in, const int* in_sizes, int n_in,
                              void* d_out, int out_size, void* d_ws, size_t ws_size,
                              hipStream_t stream)
{
    const float* X   = (const float*)d_in[0];
    const float* LN1 = (const float*)d_in[1];
    const float* LN2 = (const float*)d_in[2];
    const float* qUs = (const float*)d_in[3];
    const float* qV  = (const float*)d_in[4];
    const float* kUs = (const float*)d_in[5];
    const float* kV  = (const float*)d_in[6];
    const float* vUs = (const float*)d_in[7];
    const float* vV  = (const float*)d_in[8];
    const float* oUs = (const float*)d_in[9];
    const float* oV  = (const float*)d_in[10];
    const float* gUs = (const float*)d_in[11];
    const float* gV  = (const float*)d_in[12];
    const float* uUs = (const float*)d_in[13];
    const float* uV  = (const float*)d_in[14];
    const float* dUs = (const float*)d_in[15];
    const float* dV  = (const float*)d_in[16];
    float* OUT = (float*)d_out;

    char* w = (char*)d_ws;
    bf16*  h1   = (bf16*)(w + 0);          // [1024,4096]
    bf16*  xrq  = (bf16*)(w + 8388608);    // [1024,2048]
    bf16*  xrk  = (bf16*)(w + 12582912);   // [1024,512]
    bf16*  xrv  = (bf16*)(w + 13631488);   // [1024,512]
    bf16*  qb   = (bf16*)(w + 14680064);   // [32,1024,128]
    bf16*  kb   = (bf16*)(w + 23068672);   // [8,1024,128]
    bf16*  vt   = (bf16*)(w + 25165824);   // [8,128,1024]
    float* cs   = (float*)(w + 27262976);  // [1024,64]
    float* sn   = (float*)(w + 27525120);  // [1024,64]
    bf16*  att  = (bf16*)(w + 27787264);   // [1024,4096]
    bf16*  r1   = (bf16*)(w + 36175872);   // [1024,1024]
    bf16*  h2   = (bf16*)(w + 0);
    bf16*  gr   = (bf16*)(w + 8388608);
    bf16*  ur   = (bf16*)(w + 10485760);
    bf16*  hmid = (bf16*)(w + 12582912);   // [1024,14336]
    bf16*  dr   = (bf16*)(w + 41943040);   // [1024,1024]
    const size_t ARENA  = 44040192;
    const size_t PARTSZ = 33554432;
    float* part = (float*)(w + ARENA);
    const bool med = ws_size >= ARENA + PARTSZ;

    dim3 blk(256), blk8(512);

    if (med) {
        rmsnorm_k<<<1024, blk, 0, stream>>>(X, LN1, h1);
        // xr_q: K=4096 split 4 -> 512 blocks
        gemm8w<EPI_PART><<<dim3(128,1,4), blk8, 0, stream>>>(h1,4096,0, qV,4096,0,nullptr, part,2048,2097152, nullptr, 1024,4, 8);
        reduce_k<<<2048, blk, 0, stream>>>(part, 2097152, 4, xrq);
        // xr_k + xr_v batched (share A=h1), split 4 -> 256 blocks
        gemm8w<EPI_PART><<<dim3(32,1,8), blk8, 0, stream>>>(h1,4096,0, kV,4096,0,vV, part,512,524288, nullptr, 1024,4, 8);
        reduce_k<<<512, blk, 0, stream>>>(part,             524288, 4, xrk);
        reduce_k<<<512, blk, 0, stream>>>(part + 4L*524288, 524288, 4, xrv);

        gemm8w<EPI_BF16 ><<<dim3(8,1,32), blk8, 0, stream>>>(xrq,2048,64, qUs,64,8192,nullptr, qb,128,131072, nullptr, 64,1, 8);
        gemm8w<EPI_BF16 ><<<dim3(8,1, 8), blk8, 0, stream>>>(xrk, 512,64, kUs,64,8192,nullptr, kb,128,131072, nullptr, 64,1, 8);
        gemm8w<EPI_BF16T><<<dim3(8,1, 8), blk8, 0, stream>>>(xrv, 512,64, vUs,64,8192,nullptr, vt,1024,131072, nullptr, 64,1, 8);
        rope_table_k<<<256, blk, 0, stream>>>(cs, sn);
        rope_k<<<1024, blk, 0, stream>>>(qb, cs, sn);
        rope_k<<< 256, blk, 0, stream>>>(kb, cs, sn);
        attn_k<<<dim3(16,32), blk, 0, stream>>>(qb, kb, vt, att);

        gemm8w<EPI_PART><<<dim3(64,1,4), blk8, 0, stream>>>(att,4096,0, oV,4096,0,nullptr, part,1024,1048576, nullptr, 1024,4, 8);
        reduce_k<<<1024, blk, 0, stream>>>(part, 1048576, 4, r1);
        gemm8w<EPI_F32ADD><<<dim3(256,1,1), blk8, 0, stream>>>(r1,1024,0, oUs,1024,0,nullptr, OUT,4096,0, X, 1024,1, 8);

        rmsnorm_k<<<1024, blk, 0, stream>>>(OUT, LN2, h2);
        gemm8w<EPI_PART><<<dim3(64,1,8), blk8, 0, stream>>>(h2,4096,0, gV,4096,0,uV, part,1024,1048576, nullptr, 1024,4, 8);
        reduce_k<<<1024, blk, 0, stream>>>(part,              1048576, 4, gr);
        reduce_k<<<1024, blk, 0, stream>>>(part + 4L*1048576, 1048576, 4, ur);
        gemm8w<EPI_SILU1><<<dim3(896,1,1), blk8, 0, stream>>>(gr,1024,0, gUs,1024,0,nullptr, hmid,14336,0, nullptr, 1024,1, 8);
        gemm8w<EPI_MUL  ><<<dim3(896,1,1), blk8, 0, stream>>>(ur,1024,0, uUs,1024,0,nullptr, hmid,14336,0, nullptr, 1024,1, 8);
        gemm8w<EPI_PART ><<<dim3(64,1,7), blk8, 0, stream>>>(hmid,14336,0, dV,14336,0,nullptr, part,1024,1048576, nullptr, 2048,7, 8);
        reduce_k<<<1024, blk, 0, stream>>>(part, 1048576, 7, dr);
        gemm8w<EPI_F32ADD><<<dim3(256,1,1), blk8, 0, stream>>>(dr,1024,0, dUs,1024,0,nullptr, OUT,4096,0, OUT, 1024,1, 8);
        return;
    }

    // ---------------- fallback: gemm2 (fp32-B dbuf) path ----------------
    rmsnorm_k<<<1024, blk, 0, stream>>>(X, LN1, h1);
    gemm2<EPI_BF16><<<dim3(8,16,1), blk, 0, stream>>>(h1,4096,0, qV,4096,0,nullptr, xrq,2048,0, nullptr, 4096, 1);
    gemm2<EPI_BF16><<<dim3(8, 4,1), blk, 0, stream>>>(h1,4096,0, kV,4096,0,nullptr, xrk, 512,0, nullptr, 4096, 1);
    gemm2<EPI_BF16><<<dim3(8, 4,1), blk, 0, stream>>>(h1,4096,0, vV,4096,0,nullptr, xrv, 512,0, nullptr, 4096, 1);
    gemm2<EPI_BF16 ><<<dim3(8,1,32), blk, 0, stream>>>(xrq,2048,64, qUs,64,8192,nullptr, qb,128,131072, nullptr, 64, 1);
    gemm2<EPI_BF16 ><<<dim3(8,1, 8), blk, 0, stream>>>(xrk, 512,64, kUs,64,8192,nullptr, kb,128,131072, nullptr, 64, 1);
    gemm2<EPI_BF16T><<<dim3(8,1, 8), blk, 0, stream>>>(xrv, 512,64, vUs,64,8192,nullptr, vt,1024,131072, nullptr, 64, 1);
    rope_table_k<<<256, blk, 0, stream>>>(cs, sn);
    rope_k<<<1024, blk, 0, stream>>>(qb, cs, sn);
    rope_k<<< 256, blk, 0, stream>>>(kb, cs, sn);
    attn_k<<<dim3(16,32), blk, 0, stream>>>(qb, kb, vt, att);
    gemm2<EPI_BF16><<<dim3(8,8,1), blk, 0, stream>>>(att,4096,0, oV,4096,0,nullptr, r1,1024,0, nullptr, 4096, 1);
    gemm2<EPI_F32ADD><<<dim3(8,32,1), blk, 0, stream>>>(r1,1024,0, oUs,1024,0,nullptr, OUT,4096,0, X, 1024, 1);
    rmsnorm_k<<<1024, blk, 0, stream>>>(OUT, LN2, h2);
    gemm2<EPI_BF16><<<dim3(8,8,1), blk, 0, stream>>>(h2,4096,0, gV,4096,0,nullptr, gr,1024,0, nullptr, 4096, 1);
    gemm2<EPI_BF16><<<dim3(8,8,1), blk, 0, stream>>>(h2,4096,0, uV,4096,0,nullptr, ur,1024,0, nullptr, 4096, 1);
    gemm2<EPI_SILU1><<<dim3(8,112,1), blk, 0, stream>>>(gr,1024,0, gUs,1024,0,nullptr, hmid,14336,0, nullptr, 1024, 1);
    gemm2<EPI_MUL  ><<<dim3(8,112,1), blk, 0, stream>>>(ur,1024,0, uUs,1024,0,nullptr, hmid,14336,0, nullptr, 1024, 1);
    gemm2<EPI_BF16><<<dim3(8,8,1), blk, 0, stream>>>(hmid,14336,0, dV,14336,0,nullptr, dr,1024,0, nullptr, 14336, 1);
    gemm2<EPI_F32ADD><<<dim3(8,32,1), blk, 0, stream>>>(dr,1024,0, dUs,1024,0,nullptr, OUT,4096,0, OUT, 1024, 1);
}